// Round 10
// baseline (697.140 us; speedup 1.0000x reference)
//
#include <hip/hip_runtime.h>

// B,T,D_IN,H,LAT = 256,512,32,128,64. Wire dtype fp32 (proven R2).
#define NB   256
#define NT   512
#define NDIN 32
#define NH   128
#define NLAT 64
#define HSTR 136   // hist row stride (f16): 272B rows, b128-aligned

typedef _Float16 f16x8 __attribute__((ext_vector_type(8)));
typedef float    f32x4 __attribute__((ext_vector_type(4)));
typedef _Float16 h2    __attribute__((ext_vector_type(2)));
typedef _Float16 h4    __attribute__((ext_vector_type(4)));

__device__ __forceinline__ float dot2(h2 a, h2 b, float c) {
  return __builtin_amdgcn_fdot2(a, b, c, false);
}
__device__ __forceinline__ h2 bc2(float v) { return __builtin_bit_cast(h2, v); }
__device__ __forceinline__ h2 pk2(float a, float b) { return h2{(_Float16)a, (_Float16)b}; }

#define NLOG2E 1.44269504f
__device__ __forceinline__ float sigmoid_f(float x) {
  return __builtin_amdgcn_rcpf(1.f + __builtin_amdgcn_exp2f(x * -NLOG2E));
}
__device__ __forceinline__ float tanh_f(float x) {
  float s = __builtin_amdgcn_rcpf(1.f + __builtin_amdgcn_exp2f(x * (-2.f * NLOG2E)));
  return fmaf(2.f, s, -1.f);
}
__device__ __forceinline__ f32x4 mfma16(f16x8 a, f16x8 b, f32x4 c) {
  return __builtin_amdgcn_mfma_f32_16x16x32_f16(a, b, c, 0, 0, 0);
}

// R9 structure + GATE-GATHER activations.
// R9 measured: trans ~12 cyc/wave-instr; acts on all 8 waves = 240 cyc/SIMD
// of trans though 2 waves' worth covers all 128 units. New per-step shape:
//   phase A (8 waves): MFMA gates -> select (R9-verified) -> ds_write_b128
//                      of the unit's (i,f,g,o) to gbuf.  [barrier]
//   phase B (waves 0,1): lane u=64w+l reads gbuf[4u..4u+4), one act-set,
//                      owns c[u], writes h (+hist in dec).  [barrier]
// Trans per SIMD: 240 -> 120 (and only on 2 SIMDs); MFMA unchanged.
__global__ __launch_bounds__(512, 1) void lstm_ae_kernel(
    const float* __restrict__ x,      // [B][T][D_IN]
    const float* __restrict__ eWih,   // [4H][D_IN]
    const float* __restrict__ eWhh,   // [4H][H]
    const float* __restrict__ eBih,   // [4H]
    const float* __restrict__ eBhh,   // [4H]
    const float* __restrict__ eWl,    // [LAT][H]
    const float* __restrict__ eBl,    // [LAT]
    const float* __restrict__ dWih,   // [4H][LAT]
    const float* __restrict__ dWhh,   // [4H][H]
    const float* __restrict__ dBih,   // [4H]
    const float* __restrict__ dBhh,   // [4H]
    const float* __restrict__ dWl,    // [D_IN][H]
    const float* __restrict__ dBl,    // [D_IN]
    float* __restrict__ outE,         // [B][LAT]
    float* __restrict__ outD)         // [B][T][D_IN]
{
  extern __shared__ __align__(16) char smem[];
  float*    encs = (float*)smem;                 // [64] latent
  _Float16* hs   = (_Float16*)(encs + NLAT);     // [2][128] h double-buffer
  _Float16* hist = hs + 2 * NH;                  // [512][HSTR]
  _Float16* xs   = hist;                         // alias: [512][32] encoder x
  float*    gbuf = (float*)(hist + NT * HSTR);   // [512] gates / dec-proj

  const int tid = threadIdx.x;
  const int b   = blockIdx.x;
  const int w   = tid >> 6;       // wave 0..7
  const int l   = tid & 63;
  const int m   = l & 15;         // A-row within tile
  const int kg  = l >> 4;         // k-group 0..3
  const int ag  = m & 3;          // gate index of this lane's A-row
  const int ar  = 2 * (m >> 2);   // unit-offset part of A-row

  int au[4], cu[4];
#pragma unroll
  for (int tt = 0; tt < 4; ++tt) {
    au[tt] = 16 * w + 8 * (tt >> 1) + ar + (tt & 1);      // A-row unit
    cu[tt] = 16 * w + 8 * (tt >> 1) + 2 * kg + (tt & 1);  // C unit (this lane)
  }
  // phase-A gate writers: (l&12)==0 -> 16 lanes, distinct units cu_sel
  const bool sb0 = (l & 1) != 0, sb1 = (l & 2) != 0;
  const int  cu_sel = 16 * w + 8 * ((l >> 1) & 1) + 2 * kg + (l & 1);
  const bool gwr = (l & 12) == 0;
  // phase-B act lanes: waves 0,1; unit u = 64*w + l
  const bool actw = (w < 2);
  const int  u    = (w << 6) + l;

  // ---- stage x -> f16 LDS ----
  {
    const float4* xg = (const float4*)(x + (size_t)b * (NT * NDIN));
    h4* xo = (h4*)xs;
#pragma unroll
    for (int i = 0; i < 8; ++i) {
      int idx = i * 512 + tid;
      float4 v = xg[idx];
      xo[idx] = h4{(_Float16)v.x, (_Float16)v.y, (_Float16)v.z, (_Float16)v.w};
    }
  }

  // ---- encoder fragments ----
  f16x8 aw[4][4];   // [tile][K-block] Whh
  f16x8 ax[4];      // [tile]          Wih
  f32x4 bi[4];      // [tile]          per-gate biases of cu[tt] (MFMA C-init)
#pragma unroll
  for (int tt = 0; tt < 4; ++tt) {
    const float* r = eWhh + (size_t)(ag * NH + au[tt]) * NH;
#pragma unroll
    for (int K = 0; K < 4; ++K) {
      const float* p = r + 32 * K + 8 * kg;
#pragma unroll
      for (int j = 0; j < 8; ++j) aw[tt][K][j] = (_Float16)p[j];
    }
    const float* q = eWih + (size_t)(ag * NH + au[tt]) * NDIN + 8 * kg;
#pragma unroll
    for (int j = 0; j < 8; ++j) ax[tt][j] = (_Float16)q[j];
#pragma unroll
    for (int j = 0; j < 4; ++j)
      bi[tt][j] = eBih[j * NH + cu[tt]] + eBhh[j * NH + cu[tt]];
  }
  if (tid < 2 * NH) hs[tid] = (_Float16)0.f;
  float c = 0.f;   // live only on act lanes
  __syncthreads();

  // ============================ ENCODER ============================
#pragma unroll 1
  for (int t = 0; t < NT; ++t) {
    // ---- phase A: MFMA gates + select + gate write ----
    f32x4 acc[4];
    const _Float16* hb = hs + (t & 1) * NH;
    {
      f16x8 bf = *(const f16x8*)(hb + 8 * kg);
#pragma unroll
      for (int tt = 0; tt < 4; ++tt) acc[tt] = mfma16(aw[tt][0], bf, bi[tt]);
    }
#pragma unroll
    for (int K = 1; K < 4; ++K) {
      f16x8 bf = *(const f16x8*)(hb + 32 * K + 8 * kg);
#pragma unroll
      for (int tt = 0; tt < 4; ++tt) acc[tt] = mfma16(aw[tt][K], bf, acc[tt]);
    }
    {
      f16x8 xf = *(const f16x8*)(xs + t * NDIN + 8 * kg);
#pragma unroll
      for (int tt = 0; tt < 4; ++tt) acc[tt] = mfma16(ax[tt], xf, acc[tt]);
    }
    f32x4 ga;
#pragma unroll
    for (int j = 0; j < 4; ++j) {
      float u0 = sb1 ? acc[2][j] : acc[0][j];
      float u1 = sb1 ? acc[3][j] : acc[1][j];
      ga[j] = sb0 ? u1 : u0;
    }
    if (gwr) *(f32x4*)(gbuf + 4 * cu_sel) = ga;   // ds_write_b128, 16 lanes
    __syncthreads();

    // ---- phase B: waves 0,1 do all acts ----
    if (actw) {
      f32x4 g4 = *(const f32x4*)(gbuf + 4 * u);   // (i,f,g,o)
      float gi = sigmoid_f(g4[0]);
      float gf = sigmoid_f(g4[1]);
      float gg = tanh_f(g4[2]);
      float go = sigmoid_f(g4[3]);
      c = fmaf(gf, c, gi * gg);
      float h = go * tanh_f(c);
      hs[((t + 1) & 1) * NH + u] = (_Float16)h;
    }
    __syncthreads();
  }

  // ==================== LATENT + DECODER SETUP ====================
  // h_last in hs buffer 0 (t=511 wrote (512&1)=0)
  if (tid < NLAT) {
    const float4* p  = (const float4*)(eWl + (size_t)tid * NH);
    const float2* hh = (const float2*)hs;
    float a = eBl[tid];
#pragma unroll
    for (int r = 0; r < 32; ++r) {
      float4 wv = p[r];
      float2 hp = hh[r];
      h2 lov = bc2(hp.x), hiv = bc2(hp.y);
      a = fmaf((float)lov.x, wv.x, a); a = fmaf((float)lov.y, wv.y, a);
      a = fmaf((float)hiv.x, wv.z, a); a = fmaf((float)hiv.y, wv.w, a);
    }
    encs[tid] = a;
    outE[b * NLAT + tid] = a;
  }
#pragma unroll
  for (int tt = 0; tt < 4; ++tt) {   // decoder Whh fragments (same mapping)
    const float* r = dWhh + (size_t)(ag * NH + au[tt]) * NH;
#pragma unroll
    for (int K = 0; K < 4; ++K) {
      const float* p = r + 32 * K + 8 * kg;
#pragma unroll
      for (int j = 0; j < 8; ++j) aw[tt][K][j] = (_Float16)p[j];
    }
  }
  __syncthreads();   // latent's hs reads done; encs published

  if (tid < 2 * NH) hs[tid] = (_Float16)0.f;
  // decoder time-invariant input projection: gbuf[g] = enc@dWih[g] + biases
  {
    const float4* p  = (const float4*)(dWih + (size_t)tid * NLAT);
    const float4* e4 = (const float4*)encs;
    float a = dBih[tid] + dBhh[tid];
#pragma unroll
    for (int r = 0; r < 16; ++r) {
      float4 wv = p[r]; float4 ev = e4[r];
      a = fmaf(ev.x, wv.x, a); a = fmaf(ev.y, wv.y, a);
      a = fmaf(ev.z, wv.z, a); a = fmaf(ev.w, wv.w, a);
    }
    gbuf[tid] = a;
  }
  __syncthreads();   // gbuf + zeroed hs visible
#pragma unroll
  for (int tt = 0; tt < 4; ++tt) {
#pragma unroll
    for (int j = 0; j < 4; ++j) bi[tt][j] = gbuf[j * NH + cu[tt]];
  }
  c = 0.f;
  __syncthreads();   // all bi extracted before gbuf is reused for gates

  // ============================ DECODER ============================
#pragma unroll 1
  for (int t = 0; t < NT; ++t) {
    f32x4 acc[4];
    const _Float16* hb = hs + (t & 1) * NH;
    {
      f16x8 bf = *(const f16x8*)(hb + 8 * kg);
#pragma unroll
      for (int tt = 0; tt < 4; ++tt) acc[tt] = mfma16(aw[tt][0], bf, bi[tt]);
    }
#pragma unroll
    for (int K = 1; K < 4; ++K) {
      f16x8 bf = *(const f16x8*)(hb + 32 * K + 8 * kg);
#pragma unroll
      for (int tt = 0; tt < 4; ++tt) acc[tt] = mfma16(aw[tt][K], bf, acc[tt]);
    }
    f32x4 ga;
#pragma unroll
    for (int j = 0; j < 4; ++j) {
      float u0 = sb1 ? acc[2][j] : acc[0][j];
      float u1 = sb1 ? acc[3][j] : acc[1][j];
      ga[j] = sb0 ? u1 : u0;
    }
    if (gwr) *(f32x4*)(gbuf + 4 * cu_sel) = ga;
    __syncthreads();

    if (actw) {
      f32x4 g4 = *(const f32x4*)(gbuf + 4 * u);
      float gi = sigmoid_f(g4[0]);
      float gf = sigmoid_f(g4[1]);
      float gg = tanh_f(g4[2]);
      float go = sigmoid_f(g4[3]);
      c = fmaf(gf, c, gi * gg);
      float h = go * tanh_f(c);
      _Float16 hh = (_Float16)h;
      hs[((t + 1) & 1) * NH + u] = hh;
      hist[t * HSTR + u] = hh;
    }
    __syncthreads();
  }

  // ============ EPILOGUE: outD = hist @ dWl.T + dBl (R6-verified) ============
  {
    const int col = tid & 31, rg = tid >> 5;
    h2 wl[64];
    const float4* p0 = (const float4*)(dWl + (size_t)col * NH);
#pragma unroll
    for (int f = 0; f < 32; ++f) {
      float4 v = p0[f];
      wl[2 * f] = pk2(v.x, v.y); wl[2 * f + 1] = pk2(v.z, v.w);
    }
    const float bo = dBl[col];
    float* op = outD + (size_t)b * (NT * NDIN);
#pragma unroll 1
    for (int i = 0; i < 32; ++i) {
      int r = rg + 16 * i;
      const float4* hp = (const float4*)(hist + r * HSTR);
      float s = 0.f;
#pragma unroll
      for (int j = 0; j < 16; ++j) {
        float4 hvv = hp[j];
        s = dot2(wl[4 * j + 0], bc2(hvv.x), s);
        s = dot2(wl[4 * j + 1], bc2(hvv.y), s);
        s = dot2(wl[4 * j + 2], bc2(hvv.z), s);
        s = dot2(wl[4 * j + 3], bc2(hvv.w), s);
      }
      op[(size_t)r * NDIN + col] = s + bo;
    }
  }
}

#define SMEM_BYTES (NLAT * 4 + 2 * NH * 2 + NT * HSTR * 2 + 512 * 4)

extern "C" void kernel_launch(void* const* d_in, const int* in_sizes, int n_in,
                              void* d_out, int out_size, void* d_ws, size_t ws_size,
                              hipStream_t stream) {
  const float* x    = (const float*)d_in[0];
  const float* eWih = (const float*)d_in[1];
  const float* eWhh = (const float*)d_in[2];
  const float* eBih = (const float*)d_in[3];
  const float* eBhh = (const float*)d_in[4];
  const float* eWl  = (const float*)d_in[5];
  const float* eBl  = (const float*)d_in[6];
  const float* dWih = (const float*)d_in[7];
  const float* dWhh = (const float*)d_in[8];
  const float* dBih = (const float*)d_in[9];
  const float* dBhh = (const float*)d_in[10];
  const float* dWl  = (const float*)d_in[11];
  const float* dBl  = (const float*)d_in[12];

  float* outE = (float*)d_out;               // [256][64]
  float* outD = outE + (size_t)NB * NLAT;    // [256][512][32]

  (void)hipFuncSetAttribute((const void*)lstm_ae_kernel,
                            hipFuncAttributeMaxDynamicSharedMemorySize,
                            SMEM_BYTES);

  hipLaunchKernelGGL(lstm_ae_kernel, dim3(NB), dim3(512), SMEM_BYTES, stream,
                     x, eWih, eWhh, eBih, eBhh, eWl, eBl,
                     dWih, dWhh, dBih, dBhh, dWl, dBl, outE, outD);
}

// Round 12
// 598.525 us; speedup vs baseline: 1.1648x; 1.1648x over previous
//
#include <hip/hip_runtime.h>

// B,T,D_IN,H,LAT = 256,512,32,128,64. Wire dtype fp32 (proven R2).
#define NB   256
#define NT   512
#define NDIN 32
#define NH   128
#define NLAT 64
#define HSTR 136   // hist row stride (f16): 272B rows, b128-aligned

typedef _Float16 f16x8 __attribute__((ext_vector_type(8)));
typedef float    f32x4 __attribute__((ext_vector_type(4)));
typedef _Float16 h2    __attribute__((ext_vector_type(2)));
typedef _Float16 h4    __attribute__((ext_vector_type(4)));

__device__ __forceinline__ float dot2(h2 a, h2 b, float c) {
  return __builtin_amdgcn_fdot2(a, b, c, false);
}
__device__ __forceinline__ h2 bc2(float v) { return __builtin_bit_cast(h2, v); }
__device__ __forceinline__ h2 pk2(float a, float b) { return h2{(_Float16)a, (_Float16)b}; }

#define NLOG2E 1.44269504f
__device__ __forceinline__ float sigmoid_f(float x) {
  return __builtin_amdgcn_rcpf(1.f + __builtin_amdgcn_exp2f(x * -NLOG2E));
}
__device__ __forceinline__ float tanh_f(float x) {
  float s = __builtin_amdgcn_rcpf(1.f + __builtin_amdgcn_exp2f(x * (-2.f * NLOG2E)));
  return fmaf(2.f, s, -1.f);
}
__device__ __forceinline__ f32x4 mfma16(f16x8 a, f16x8 b, f32x4 c) {
  return __builtin_amdgcn_mfma_f32_16x16x32_f16(a, b, c, 0, 0, 0);
}

// DPP row-rotate semantics (R11 ERRATA, fixed here): AMD "rotate RIGHT by N"
// moves data toward HIGHER lanes: dst[i] = src[(i-N) & 15] (proven by the
// canonical row_shr scan idiom v[i]+=v[i-N]). To pull from lane p+D into
// lane p, use row_ror:(16-D).
template <int CTRL>
__device__ __forceinline__ float dpp_mov(float v) {
  int p = __builtin_amdgcn_update_dpp(0, __builtin_bit_cast(int, v),
                                      CTRL, 0xF, 0xF, true);
  return __builtin_bit_cast(float, p);
}
#define ROR4  0x124   // dst[p] = src[p+12]
#define ROR8  0x128   // dst[p] = src[p+8]
#define ROR12 0x12C   // dst[p] = src[p+4]

// R9 single-barrier structure (617 us, verified) + DISTRIBUTED-GATE acts.
// Lane p of a 16-lane row activates ONE gate: gate (p>>2)&3 of unit sel(p&3);
// rotates deliver f,g,o to the i-lane (p<4, == R9's writer) for the c/h
// chain. Per-wave transcendentals 10 -> 4. R11 failed only on the rotate
// direction (f/o swapped); this round swaps ROR4<->ROR12 usage.
__global__ __launch_bounds__(512, 1) void lstm_ae_kernel(
    const float* __restrict__ x,      // [B][T][D_IN]
    const float* __restrict__ eWih,   // [4H][D_IN]
    const float* __restrict__ eWhh,   // [4H][H]
    const float* __restrict__ eBih,   // [4H]
    const float* __restrict__ eBhh,   // [4H]
    const float* __restrict__ eWl,    // [LAT][H]
    const float* __restrict__ eBl,    // [LAT]
    const float* __restrict__ dWih,   // [4H][LAT]
    const float* __restrict__ dWhh,   // [4H][H]
    const float* __restrict__ dBih,   // [4H]
    const float* __restrict__ dBhh,   // [4H]
    const float* __restrict__ dWl,    // [D_IN][H]
    const float* __restrict__ dBl,    // [D_IN]
    float* __restrict__ outE,         // [B][LAT]
    float* __restrict__ outD)         // [B][T][D_IN]
{
  extern __shared__ __align__(16) char smem[];
  float*    encs = (float*)smem;                 // [64] latent
  _Float16* hs   = (_Float16*)(encs + NLAT);     // [2][128] h double-buffer
  _Float16* hist = hs + 2 * NH;                  // [512][HSTR]
  _Float16* xs   = hist;                         // alias: [512][32] encoder x
  float*    gtmp = (float*)(hist + NT * HSTR);   // [512] dec input projection

  const int tid = threadIdx.x;
  const int b   = blockIdx.x;
  const int w   = tid >> 6;       // wave 0..7
  const int l   = tid & 63;
  const int m   = l & 15;         // A-row within tile
  const int kg  = l >> 4;         // k-group 0..3
  const int ag  = m & 3;          // gate index of this lane's A-row
  const int ar  = 2 * (m >> 2);   // unit-offset part of A-row

  int au[4], cu[4];
#pragma unroll
  for (int tt = 0; tt < 4; ++tt) {
    au[tt] = 16 * w + 8 * (tt >> 1) + ar + (tt & 1);      // A-row unit
    cu[tt] = 16 * w + 8 * (tt >> 1) + 2 * kg + (tt & 1);  // C unit (this lane)
  }
  // act distribution: lane handles gate gj=(l>>2)&3 of unit sel=(l&3)
  const bool sb0 = (l & 1) != 0, sb1 = (l & 2) != 0;   // tile-select bits
  const bool b2  = (l & 4) != 0, b3  = (l & 8) != 0;   // gate-select bits
  const int  cu_sel = 16 * w + 8 * ((l >> 1) & 1) + 2 * kg + (l & 1);
  const bool writer = (l & 12) == 0;   // gj==0 (i-gate lane) owns c/h
  const bool gthn   = b3 && !b2;       // gj==2 -> tanh gate
  const float km = gthn ? (-2.f * NLOG2E) : -NLOG2E;   // pre-scale
  const float pa = gthn ? 2.f : 1.f;                   // post fixup a*s+b
  const float pb = gthn ? -1.f : 0.f;

  // ---- stage x -> f16 LDS ----
  {
    const float4* xg = (const float4*)(x + (size_t)b * (NT * NDIN));
    h4* xo = (h4*)xs;
#pragma unroll
    for (int i = 0; i < 8; ++i) {
      int idx = i * 512 + tid;
      float4 v = xg[idx];
      xo[idx] = h4{(_Float16)v.x, (_Float16)v.y, (_Float16)v.z, (_Float16)v.w};
    }
  }

  // ---- encoder fragments ----
  f16x8 aw[4][4];   // [tile][K-block] Whh
  f16x8 ax[4];      // [tile]          Wih
  f32x4 bi[4];      // [tile]          per-gate biases of cu[tt] (MFMA C-init)
#pragma unroll
  for (int tt = 0; tt < 4; ++tt) {
    const float* r = eWhh + (size_t)(ag * NH + au[tt]) * NH;
#pragma unroll
    for (int K = 0; K < 4; ++K) {
      const float* p = r + 32 * K + 8 * kg;
#pragma unroll
      for (int j = 0; j < 8; ++j) aw[tt][K][j] = (_Float16)p[j];
    }
    const float* q = eWih + (size_t)(ag * NH + au[tt]) * NDIN + 8 * kg;
#pragma unroll
    for (int j = 0; j < 8; ++j) ax[tt][j] = (_Float16)q[j];
#pragma unroll
    for (int j = 0; j < 4; ++j)
      bi[tt][j] = eBih[j * NH + cu[tt]] + eBhh[j * NH + cu[tt]];
  }
  if (tid < 2 * NH) hs[tid] = (_Float16)0.f;
  float c = 0.f;   // meaningful only on writer lanes
  __syncthreads();

  // ============================ ENCODER ============================
#pragma unroll 1
  for (int t = 0; t < NT; ++t) {
    f32x4 acc[4];
    const _Float16* hb = hs + (t & 1) * NH;
    {
      f16x8 bf = *(const f16x8*)(hb + 8 * kg);
#pragma unroll
      for (int tt = 0; tt < 4; ++tt) acc[tt] = mfma16(aw[tt][0], bf, bi[tt]);
    }
#pragma unroll
    for (int K = 1; K < 4; ++K) {
      f16x8 bf = *(const f16x8*)(hb + 32 * K + 8 * kg);
#pragma unroll
      for (int tt = 0; tt < 4; ++tt) acc[tt] = mfma16(aw[tt][K], bf, acc[tt]);
    }
    {
      f16x8 xf = *(const f16x8*)(xs + t * NDIN + 8 * kg);
#pragma unroll
      for (int tt = 0; tt < 4; ++tt) acc[tt] = mfma16(ax[tt], xf, acc[tt]);
    }
    // select z = acc[sel][gj]  (15 cndmask)
    float z;
    {
      float v0, v1, v2, v3;
      {
        float u0 = b3 ? acc[0][2] : acc[0][0], u1 = b3 ? acc[0][3] : acc[0][1];
        v0 = b2 ? u1 : u0;
      }
      {
        float u0 = b3 ? acc[1][2] : acc[1][0], u1 = b3 ? acc[1][3] : acc[1][1];
        v1 = b2 ? u1 : u0;
      }
      {
        float u0 = b3 ? acc[2][2] : acc[2][0], u1 = b3 ? acc[2][3] : acc[2][1];
        v2 = b2 ? u1 : u0;
      }
      {
        float u0 = b3 ? acc[3][2] : acc[3][0], u1 = b3 ? acc[3][3] : acc[3][1];
        v3 = b2 ? u1 : u0;
      }
      float w0 = sb1 ? v2 : v0, w1 = sb1 ? v3 : v1;
      z = sb0 ? w1 : w0;
    }
    // one activation per lane
    float a = fmaf(pa, __builtin_amdgcn_rcpf(1.f + __builtin_amdgcn_exp2f(z * km)), pb);
    // gather f,g,o to the i-lane: pull from p+4 / p+8 / p+12
    float vf = dpp_mov<ROR12>(a);   // src p+4  (f)
    float vg = dpp_mov<ROR8>(a);    // src p+8  (g)
    float vo = dpp_mov<ROR4>(a);    // src p+12 (o)
    c = fmaf(vf, c, a * vg);        // a == i on writer lanes
    float h = vo * tanh_f(c);
    if (writer) hs[((t + 1) & 1) * NH + cu_sel] = (_Float16)h;
    __syncthreads();
  }

  // ==================== LATENT + DECODER SETUP ====================
  // h_last in hs buffer 0 (t=511 wrote (512&1)=0)
  if (tid < NLAT) {
    const float4* p  = (const float4*)(eWl + (size_t)tid * NH);
    const float2* hh = (const float2*)hs;
    float a = eBl[tid];
#pragma unroll
    for (int r = 0; r < 32; ++r) {
      float4 wv = p[r];
      float2 hp = hh[r];
      h2 lov = bc2(hp.x), hiv = bc2(hp.y);
      a = fmaf((float)lov.x, wv.x, a); a = fmaf((float)lov.y, wv.y, a);
      a = fmaf((float)hiv.x, wv.z, a); a = fmaf((float)hiv.y, wv.w, a);
    }
    encs[tid] = a;
    outE[b * NLAT + tid] = a;
  }
#pragma unroll
  for (int tt = 0; tt < 4; ++tt) {   // decoder Whh fragments (same mapping)
    const float* r = dWhh + (size_t)(ag * NH + au[tt]) * NH;
#pragma unroll
    for (int K = 0; K < 4; ++K) {
      const float* p = r + 32 * K + 8 * kg;
#pragma unroll
      for (int j = 0; j < 8; ++j) aw[tt][K][j] = (_Float16)p[j];
    }
  }
  __syncthreads();   // latent's hs reads done; encs published

  if (tid < 2 * NH) hs[tid] = (_Float16)0.f;
  // decoder time-invariant input projection: gtmp[g] = enc@dWih[g] + biases
  {
    const float4* p  = (const float4*)(dWih + (size_t)tid * NLAT);
    const float4* e4 = (const float4*)encs;
    float a = dBih[tid] + dBhh[tid];
#pragma unroll
    for (int r = 0; r < 16; ++r) {
      float4 wv = p[r]; float4 ev = e4[r];
      a = fmaf(ev.x, wv.x, a); a = fmaf(ev.y, wv.y, a);
      a = fmaf(ev.z, wv.z, a); a = fmaf(ev.w, wv.w, a);
    }
    gtmp[tid] = a;
  }
  __syncthreads();   // gtmp + zeroed hs visible
#pragma unroll
  for (int tt = 0; tt < 4; ++tt) {
#pragma unroll
    for (int j = 0; j < 4; ++j) bi[tt][j] = gtmp[j * NH + cu[tt]];
  }
  c = 0.f;

  // ============================ DECODER ============================
#pragma unroll 1
  for (int t = 0; t < NT; ++t) {
    f32x4 acc[4];
    const _Float16* hb = hs + (t & 1) * NH;
    {
      f16x8 bf = *(const f16x8*)(hb + 8 * kg);
#pragma unroll
      for (int tt = 0; tt < 4; ++tt) acc[tt] = mfma16(aw[tt][0], bf, bi[tt]);
    }
#pragma unroll
    for (int K = 1; K < 4; ++K) {
      f16x8 bf = *(const f16x8*)(hb + 32 * K + 8 * kg);
#pragma unroll
      for (int tt = 0; tt < 4; ++tt) acc[tt] = mfma16(aw[tt][K], bf, acc[tt]);
    }
    float z;
    {
      float v0, v1, v2, v3;
      {
        float u0 = b3 ? acc[0][2] : acc[0][0], u1 = b3 ? acc[0][3] : acc[0][1];
        v0 = b2 ? u1 : u0;
      }
      {
        float u0 = b3 ? acc[1][2] : acc[1][0], u1 = b3 ? acc[1][3] : acc[1][1];
        v1 = b2 ? u1 : u0;
      }
      {
        float u0 = b3 ? acc[2][2] : acc[2][0], u1 = b3 ? acc[2][3] : acc[2][1];
        v2 = b2 ? u1 : u0;
      }
      {
        float u0 = b3 ? acc[3][2] : acc[3][0], u1 = b3 ? acc[3][3] : acc[3][1];
        v3 = b2 ? u1 : u0;
      }
      float w0 = sb1 ? v2 : v0, w1 = sb1 ? v3 : v1;
      z = sb0 ? w1 : w0;
    }
    float a = fmaf(pa, __builtin_amdgcn_rcpf(1.f + __builtin_amdgcn_exp2f(z * km)), pb);
    float vf = dpp_mov<ROR12>(a);   // src p+4  (f)
    float vg = dpp_mov<ROR8>(a);    // src p+8  (g)
    float vo = dpp_mov<ROR4>(a);    // src p+12 (o)
    c = fmaf(vf, c, a * vg);
    float h = vo * tanh_f(c);
    if (writer) {
      _Float16 hh = (_Float16)h;
      hs[((t + 1) & 1) * NH + cu_sel] = hh;
      hist[t * HSTR + cu_sel] = hh;
    }
    __syncthreads();
  }

  // ============ EPILOGUE: outD = hist @ dWl.T + dBl (R6-verified) ============
  {
    const int col = tid & 31, rg = tid >> 5;
    h2 wl[64];
    const float4* p0 = (const float4*)(dWl + (size_t)col * NH);
#pragma unroll
    for (int f = 0; f < 32; ++f) {
      float4 v = p0[f];
      wl[2 * f] = pk2(v.x, v.y); wl[2 * f + 1] = pk2(v.z, v.w);
    }
    const float bo = dBl[col];
    float* op = outD + (size_t)b * (NT * NDIN);
#pragma unroll 1
    for (int i = 0; i < 32; ++i) {
      int r = rg + 16 * i;
      const float4* hp = (const float4*)(hist + r * HSTR);
      float s = 0.f;
#pragma unroll
      for (int j = 0; j < 16; ++j) {
        float4 hvv = hp[j];
        s = dot2(wl[4 * j + 0], bc2(hvv.x), s);
        s = dot2(wl[4 * j + 1], bc2(hvv.y), s);
        s = dot2(wl[4 * j + 2], bc2(hvv.z), s);
        s = dot2(wl[4 * j + 3], bc2(hvv.w), s);
      }
      op[(size_t)r * NDIN + col] = s + bo;
    }
  }
}

#define SMEM_BYTES (NLAT * 4 + 2 * NH * 2 + NT * HSTR * 2 + 512 * 4)

extern "C" void kernel_launch(void* const* d_in, const int* in_sizes, int n_in,
                              void* d_out, int out_size, void* d_ws, size_t ws_size,
                              hipStream_t stream) {
  const float* x    = (const float*)d_in[0];
  const float* eWih = (const float*)d_in[1];
  const float* eWhh = (const float*)d_in[2];
  const float* eBih = (const float*)d_in[3];
  const float* eBhh = (const float*)d_in[4];
  const float* eWl  = (const float*)d_in[5];
  const float* eBl  = (const float*)d_in[6];
  const float* dWih = (const float*)d_in[7];
  const float* dWhh = (const float*)d_in[8];
  const float* dBih = (const float*)d_in[9];
  const float* dBhh = (const float*)d_in[10];
  const float* dWl  = (const float*)d_in[11];
  const float* dBl  = (const float*)d_in[12];

  float* outE = (float*)d_out;               // [256][64]
  float* outD = outE + (size_t)NB * NLAT;    // [256][512][32]

  (void)hipFuncSetAttribute((const void*)lstm_ae_kernel,
                            hipFuncAttributeMaxDynamicSharedMemorySize,
                            SMEM_BYTES);

  hipLaunchKernelGGL(lstm_ae_kernel, dim3(NB), dim3(512), SMEM_BYTES, stream,
                     x, eWih, eWhh, eBih, eBhh, eWl, eBl,
                     dWih, dWhh, dBih, dBhh, dWl, dBl, outE, outD);
}